// Round 12
// baseline (119.519 us; speedup 1.0000x reference)
//
#include <hip/hip_runtime.h>
#include <hip/hip_fp16.h>
#include <math.h>

namespace {

constexpr int BB  = 4;    // batch
constexpr int SS  = 512;  // detector bins == image size
constexpr int AA  = 180;  // angles
constexpr int RST = 520;  // global row stride in __half2: [0,4) zeros, [4,516) data, [516,520) zeros

typedef float v2f __attribute__((ext_vector_type(2)));

// ---------------------------------------------------------------------------
// Kernel A: zero `out` + ramp filter + fp16 pair-pack into PADDED global rows.
//   row[4+j] = (half(y[j]), half(y[511-j])); row[0..3] = row[516..519] = 0.
// Pads give exact grid_sample zero-padding semantics for p in (-eps,0) and
// p > 511 without any LDS pad machinery in kernel B.
// Conv math identical to R4-verified version (absmax 9.77e-4).
// ---------------------------------------------------------------------------
__global__ __launch_bounds__(256) void ramp_zero_kernel(
    const float* __restrict__ x, __half2* __restrict__ xf2, float* __restrict__ out) {
  const int t = threadIdx.x;
  {  // zero out: 262144 float4 over 360 blocks
    const int bid = blockIdx.y * 90 + blockIdx.x;
    float4 z = make_float4(0.f, 0.f, 0.f, 0.f);
    for (int i = bid * 256 + t; i < (BB * SS * SS) / 4; i += 360 * 256)
      ((float4*)out)[i] = z;
  }

  __shared__ __align__(16) float xs[2][2][256];  // [col][m-parity][m>>1]
  __shared__ __align__(16) float G[2][528];      // per-parity scaled taps
  __shared__ float yb[2][512];                   // filtered rows (both cols)
  const int a0 = blockIdx.x * 2;
  const int b  = blockIdx.y;

  const float s  = (float)(M_PI / 360.0);
  const float cc = (float)(-2.0 / (M_PI * M_PI)) * s;
  for (int i = t; i < 528; i += 256) {
    { int kk = i;     float d = (float)(2 * kk - 511); G[0][i] = (kk < 512) ? cc / (d * d) : 0.0f; }
    { int kk = i + 1; float d = (float)(2 * kk - 511); G[1][i] = (kk < 512) ? cc / (d * d) : 0.0f; }
  }

  const float* xb = x + (size_t)b * (SS * AA) + a0;
  {
    int m = t;
    float2 v = *(const float2*)(xb + (size_t)m * AA);
    xs[0][m & 1][m >> 1] = v.x;  xs[1][m & 1][m >> 1] = v.y;
    m = t + 256;
    float2 v2 = *(const float2*)(xb + (size_t)m * AA);
    xs[0][m & 1][m >> 1] = v2.x; xs[1][m & 1][m >> 1] = v2.y;
  }
  __syncthreads();

  const int col = t >> 7;
  const int p   = (t >> 6) & 1;
  const int idx = t & 63;
  const float* Gp = G[p];
  const float* xv = xs[col][1 - p];

  float acc[4] = {0.f, 0.f, 0.f, 0.f};
  float W[8];  // W[s] = Gp[A0 + s], A0 = 4*idx + 252 - 4q; slot(r,d) = 3+r-d
  {
    const int A0 = 4 * idx + 252;
    float4 w0 = *(const float4*)(Gp + A0);
    float4 w1 = *(const float4*)(Gp + A0 + 4);
    W[0] = w0.x; W[1] = w0.y; W[2] = w0.z; W[3] = w0.w;
    W[4] = w1.x; W[5] = w1.y; W[6] = w1.z; W[7] = w1.w;
  }

#pragma unroll
  for (int q = 0; q < 64; ++q) {
    const float4 xq = *(const float4*)(xv + 4 * q);  // broadcast
    float4 nw;
    if (q != 63) nw = *(const float4*)(Gp + (4 * idx + 252 - 4 * (q + 1)));
#pragma unroll
    for (int r = 0; r < 4; ++r) {
      acc[r] = fmaf(W[3 + r], xq.x, acc[r]);
      acc[r] = fmaf(W[2 + r], xq.y, acc[r]);
      acc[r] = fmaf(W[1 + r], xq.z, acc[r]);
      acc[r] = fmaf(W[0 + r], xq.w, acc[r]);
    }
    if (q != 63) {
      W[7] = W[3]; W[6] = W[2]; W[5] = W[1]; W[4] = W[0];
      W[0] = nw.x; W[1] = nw.y; W[2] = nw.z; W[3] = nw.w;
    }
  }

  // self term -> LDS row (yb is a distinct array: no barrier needed before)
  const float selfc = 0.5f * s;
  const float* xsp = xs[col][p];
#pragma unroll
  for (int r = 0; r < 4; ++r)
    yb[col][p + 8 * idx + 2 * r] = fmaf(selfc, xsp[4 * idx + r], acc[r]);
  __syncthreads();

  // pack (fwd, rev) fp16 pairs into padded rows, coalesced 4B stores
  __half2* orow = xf2 + (size_t)(b * AA + a0) * RST;
#pragma unroll
  for (int e = 0; e < 2; ++e) {
    int j = t + e * 256;
#pragma unroll
    for (int c2 = 0; c2 < 2; ++c2)
      orow[c2 * RST + 4 + j] = __floats2half2_rn(yb[c2][j], yb[c2][511 - j]);
  }
  if (t < 16) {  // zero pads: 2 cols x {[0,4) U [516,520)}
    int c2 = t >> 3, o = t & 7;
    int j = (o < 4) ? o : (512 + o);
    orow[c2 * RST + j] = __floats2half2_rn(0.f, 0.f);
  }
}

// ---------------------------------------------------------------------------
// Kernel B: backprojection — direct L2 gather, NO LDS staging/barriers.
// R12 vs R11 (bp ~38us): xf2 is only 1.5MB (L2-resident per XCD); the LDS
// round-trip (15 DMA-drain barriers + staging + pads) was pure overhead over
// the ~11us VALU / ~6us L2 floors. Now each sample-pair is:
//   1 fma + cvt + med3 clamp + fract + 8B global gather + 3 pk-f16 ops.
// Point-reflection pairing kept: row[4+j]=(y[j],y[511-j]) => pixels (gx,gy)
// and (511-gx,511-gy) share (I,w) and one load. Padded rows make boundary
// cases exact; out-circle lanes clamp to in-row garbage (finite, masked).
// Grid (4,32,16) = 2048 blocks = 8/CU = 32 waves/CU, no LDS limit.
// ---------------------------------------------------------------------------
__global__ __launch_bounds__(256, 8) void backproject_kernel(
    const __half2* __restrict__ xf2, float* __restrict__ out) {
  __shared__ float2 trig[45];

  const int t     = threadIdx.x;
  const int w     = t >> 6;
  const int lane  = t & 63;
  const int tx    = blockIdx.x;     // 0..3  x-tile (64 px, left half)
  const int ty    = blockIdx.y;     // 0..31 y-tile (16 rows of pairs)
  const int b     = blockIdx.z >> 2;
  const int chunk = blockIdx.z & 3;
  const int a0    = chunk * 45;

  // early-exit tiles fully outside the circle (mirror shares |x|,|y|)
  {
    const float step = 2.0f / 511.0f;
    float x0 = -1.0f + (float)(tx * 64) * step, x1 = -1.0f + (float)(tx * 64 + 63) * step;
    float y0 = -1.0f + (float)(ty * 16) * step, y1 = -1.0f + (float)(ty * 16 + 15) * step;
    float mx = (x0 <= 0.f && x1 >= 0.f) ? 0.f : fminf(fabsf(x0), fabsf(x1));
    float my = (y0 <= 0.f && y1 >= 0.f) ? 0.f : fminf(fabsf(y0), fabsf(y1));
    if (mx * mx + my * my > 1.0f) return;  // out already zeroed
  }

  if (t < 45) {
    float th = (float)(a0 + t) * (float)(M_PI / 180.0);
    float sn, cn;
    sincosf(th, &sn, &cn);
    trig[t] = make_float2(cn * 255.5f, sn * 255.5f);
  }
  __syncthreads();

  const __half2* src = xf2 + (size_t)(b * AA + a0) * RST;

  const int gx = tx * 64 + lane;    // [0,256)
  // EXACT f32 replication of jnp.linspace for the MASK (discontinuous);
  // p itself is continuity-safe.
  const float step = 2.0f / 511.0f;
  const float xg = __fadd_rn(-1.0f, __fmul_rn((float)gx, step));
  float dy[4];
#pragma unroll
  for (int kk = 0; kk < 4; ++kk) {
    int gy = ty * 16 + w + 4 * kk;
    dy[kk] = -__fadd_rn(-1.0f, __fmul_rn((float)gy, step));
  }

  const float Kb = 255.5f + 4.0f;   // +4 = global row pad offset; P > 0 in-circle
  v2f acc[4];
#pragma unroll
  for (int kk = 0; kk < 4; ++kk) acc[kk] = (v2f){0.f, 0.f};

  const __half2 hz2 = __floats2half2_rn(0.f, 0.f);
  for (int g = 0; g < 9; ++g) {           // 9 groups x 5 angles
    __half2 gacc[4] = {hz2, hz2, hz2, hz2};
#pragma unroll
    for (int aa = 0; aa < 5; ++aa) {
      const int a = g * 5 + aa;
      const float2 cs = trig[a];
      const float base = fmaf(xg, cs.x, Kb);
      const __half2* R = src + a * RST;
#pragma unroll
      for (int kk = 0; kk < 4; ++kk) {
        float P = fmaf(dy[kk], cs.y, base);   // in-circle: P in [3.99, 515.1)
        int   I = (int)P;                     // trunc == floor for P > 0
        I = min(max(I, 0), 518);              // v_med3: contain out-circle garbage
#if __has_builtin(__builtin_amdgcn_fractf)
        float wq = __builtin_amdgcn_fractf(P);
#else
        float wq = P - floorf(P);
#endif
        struct { __half2 a, b; } q;           // 8B gather from L1/L2
        __builtin_memcpy(&q, R + I, 8);
        __half2 dv  = __hsub2(q.b, q.a);
        __half2 wh2 = __floats2half2_rn(wq, wq);
        gacc[kk] = __hadd2(gacc[kk], __hfma2(wh2, dv, q.a));
      }
    }
    // flush fp16 group accumulator (5 samples, |val| <= ~0.3) to f32
#pragma unroll
    for (int kk = 0; kk < 4; ++kk) {
      float2 f = __half22float2(gacc[kk]);
      acc[kk].x += f.x;
      acc[kk].y += f.y;
    }
  }

  // epilogue: per-pixel masks (exact f32 replication) + predicated atomics
  const int gxm  = 511 - gx;
  const float xgm = __fadd_rn(-1.0f, __fmul_rn((float)gxm, step));
  const float xx  = __fmul_rn(xg, xg);
  const float xxm = __fmul_rn(xgm, xgm);
#pragma unroll
  for (int kk = 0; kk < 4; ++kk) {
    int gy  = ty * 16 + w + 4 * kk;
    float yg = -dy[kk];
    float s0 = __fadd_rn(xx, __fmul_rn(yg, yg));
    if (s0 <= 1.0f)
      unsafeAtomicAdd(&out[((size_t)b * SS + gy) * SS + gx], acc[kk].x);
    int gym = 511 - gy;
    float ygm = __fadd_rn(-1.0f, __fmul_rn((float)gym, step));
    float s1 = __fadd_rn(xxm, __fmul_rn(ygm, ygm));
    if (s1 <= 1.0f)
      unsafeAtomicAdd(&out[((size_t)b * SS + gym) * SS + gxm], acc[kk].y);
  }
}

}  // namespace

extern "C" void kernel_launch(void* const* d_in, const int* in_sizes, int n_in,
                              void* d_out, int out_size, void* d_ws, size_t ws_size,
                              hipStream_t stream) {
  const float* x   = (const float*)d_in[0];
  float*       out = (float*)d_out;
  __half2*     xf2 = (__half2*)d_ws;  // [B*A][520] x 4B = 1.50 MB

  ramp_zero_kernel<<<dim3(AA / 2, BB), 256, 0, stream>>>(x, xf2, out);
  backproject_kernel<<<dim3(4, 32, 16), 256, 0, stream>>>(xf2, out);
}

// Round 13
// 98.632 us; speedup vs baseline: 1.2118x; 1.2118x over previous
//
#include <hip/hip_runtime.h>
#include <hip/hip_fp16.h>
#include <math.h>

namespace {

constexpr int BB  = 4;    // batch
constexpr int SS  = 512;  // detector bins == image size
constexpr int AA  = 180;  // angles
constexpr int RST = 520;  // row stride in __half2: [0,4) zeros, [4,516) data, [516,520) zeros

typedef float v2f __attribute__((ext_vector_type(2)));

// ---------------------------------------------------------------------------
// Kernel A: zero `out` + ramp filter + fp16 pair-pack into PADDED global rows.
//   row[4+j] = (half(y[j]), half(y[511-j])); row[0..3] = row[516..519] = 0.
// (R12-verified, absmax 9.77e-4.)
// ---------------------------------------------------------------------------
__global__ __launch_bounds__(256) void ramp_zero_kernel(
    const float* __restrict__ x, __half2* __restrict__ xf2, float* __restrict__ out) {
  const int t = threadIdx.x;
  {  // zero out: 262144 float4 over 360 blocks
    const int bid = blockIdx.y * 90 + blockIdx.x;
    float4 z = make_float4(0.f, 0.f, 0.f, 0.f);
    for (int i = bid * 256 + t; i < (BB * SS * SS) / 4; i += 360 * 256)
      ((float4*)out)[i] = z;
  }

  __shared__ __align__(16) float xs[2][2][256];  // [col][m-parity][m>>1]
  __shared__ __align__(16) float G[2][528];      // per-parity scaled taps
  __shared__ float yb[2][512];                   // filtered rows (both cols)
  const int a0 = blockIdx.x * 2;
  const int b  = blockIdx.y;

  const float s  = (float)(M_PI / 360.0);
  const float cc = (float)(-2.0 / (M_PI * M_PI)) * s;
  for (int i = t; i < 528; i += 256) {
    { int kk = i;     float d = (float)(2 * kk - 511); G[0][i] = (kk < 512) ? cc / (d * d) : 0.0f; }
    { int kk = i + 1; float d = (float)(2 * kk - 511); G[1][i] = (kk < 512) ? cc / (d * d) : 0.0f; }
  }

  const float* xb = x + (size_t)b * (SS * AA) + a0;
  {
    int m = t;
    float2 v = *(const float2*)(xb + (size_t)m * AA);
    xs[0][m & 1][m >> 1] = v.x;  xs[1][m & 1][m >> 1] = v.y;
    m = t + 256;
    float2 v2 = *(const float2*)(xb + (size_t)m * AA);
    xs[0][m & 1][m >> 1] = v2.x; xs[1][m & 1][m >> 1] = v2.y;
  }
  __syncthreads();

  const int col = t >> 7;
  const int p   = (t >> 6) & 1;
  const int idx = t & 63;
  const float* Gp = G[p];
  const float* xv = xs[col][1 - p];

  float acc[4] = {0.f, 0.f, 0.f, 0.f};
  float W[8];  // W[s] = Gp[A0 + s], A0 = 4*idx + 252 - 4q; slot(r,d) = 3+r-d
  {
    const int A0 = 4 * idx + 252;
    float4 w0 = *(const float4*)(Gp + A0);
    float4 w1 = *(const float4*)(Gp + A0 + 4);
    W[0] = w0.x; W[1] = w0.y; W[2] = w0.z; W[3] = w0.w;
    W[4] = w1.x; W[5] = w1.y; W[6] = w1.z; W[7] = w1.w;
  }

#pragma unroll
  for (int q = 0; q < 64; ++q) {
    const float4 xq = *(const float4*)(xv + 4 * q);  // broadcast
    float4 nw;
    if (q != 63) nw = *(const float4*)(Gp + (4 * idx + 252 - 4 * (q + 1)));
#pragma unroll
    for (int r = 0; r < 4; ++r) {
      acc[r] = fmaf(W[3 + r], xq.x, acc[r]);
      acc[r] = fmaf(W[2 + r], xq.y, acc[r]);
      acc[r] = fmaf(W[1 + r], xq.z, acc[r]);
      acc[r] = fmaf(W[0 + r], xq.w, acc[r]);
    }
    if (q != 63) {
      W[7] = W[3]; W[6] = W[2]; W[5] = W[1]; W[4] = W[0];
      W[0] = nw.x; W[1] = nw.y; W[2] = nw.z; W[3] = nw.w;
    }
  }

  // self term -> LDS row (yb is a distinct array: no barrier needed before)
  const float selfc = 0.5f * s;
  const float* xsp = xs[col][p];
#pragma unroll
  for (int r = 0; r < 4; ++r)
    yb[col][p + 8 * idx + 2 * r] = fmaf(selfc, xsp[4 * idx + r], acc[r]);
  __syncthreads();

  // pack (fwd, rev) fp16 pairs into padded rows, coalesced 4B stores
  __half2* orow = xf2 + (size_t)(b * AA + a0) * RST;
#pragma unroll
  for (int e = 0; e < 2; ++e) {
    int j = t + e * 256;
#pragma unroll
    for (int c2 = 0; c2 < 2; ++c2)
      orow[c2 * RST + 4 + j] = __floats2half2_rn(yb[c2][j], yb[c2][511 - j]);
  }
  if (t < 16) {  // zero pads: 2 cols x {[0,4) U [516,520)}
    int c2 = t >> 3, o = t & 7;
    int j = (o < 4) ? o : (512 + o);
    orow[c2 * RST + j] = __floats2half2_rn(0.f, 0.f);
  }
}

// ---------------------------------------------------------------------------
// Kernel B: backprojection — WAVE-PRIVATE LDS double buffers, ZERO barriers.
// R13 vs R11 (~38us: 15 __syncthreads+vmcnt(0) drains = ~20us overhead) and
// R12 (62us: L1 gather splits on divergent addrs): each wave stages rows into
// its OWN padded 520-entry LDS buffer (global->VGPR->ds_write; same-wave DS
// ordering needs no barrier), double-buffered per angle. 4x staging traffic
// (L2-resident, ~5us aggregate) buys ZERO cross-wave synchronization.
// Point-reflection pairing kept (row[4+j]=(y[j],y[511-j]): mirror pixel
// shares I,w and the 8B ds_read2_b32). Packed-fp16 lerp (R11-verified).
// Grid (4,16,16) = 1024 blocks = 4/CU = 16 waves/CU; LDS 17KB; kk=8 pairs.
// ---------------------------------------------------------------------------
__global__ __launch_bounds__(256, 4) void backproject_kernel(
    const __half2* __restrict__ xf2, float* __restrict__ out) {
  __shared__ __align__(16) __half2 bufs[4][2][RST];  // wave-private, 16.6 KB
  __shared__ float2 trig[45];

  const int t     = threadIdx.x;
  const int w     = t >> 6;
  const int lane  = t & 63;
  const int tx    = blockIdx.x;     // 0..3  x-tile (64 px, left half)
  const int ty    = blockIdx.y;     // 0..15 y-tile (32 rows of pairs)
  const int b     = blockIdx.z >> 2;
  const int chunk = blockIdx.z & 3;
  const int a0    = chunk * 45;

  // early-exit tiles fully outside the circle (block-uniform; before barrier)
  {
    const float step = 2.0f / 511.0f;
    float x0 = -1.0f + (float)(tx * 64) * step, x1 = -1.0f + (float)(tx * 64 + 63) * step;
    float y0 = -1.0f + (float)(ty * 32) * step, y1 = -1.0f + (float)(ty * 32 + 31) * step;
    float mx = (x0 <= 0.f && x1 >= 0.f) ? 0.f : fminf(fabsf(x0), fabsf(x1));
    float my = (y0 <= 0.f && y1 >= 0.f) ? 0.f : fminf(fabsf(y0), fabsf(y1));
    if (mx * mx + my * my > 1.0f) return;  // out already zeroed
  }

  if (t < 45) {
    float th = (float)(a0 + t) * (float)(M_PI / 180.0);
    float sn, cn;
    sincosf(th, &sn, &cn);
    trig[t] = make_float2(cn * 255.5f, sn * 255.5f);
  }
  // zero this wave's buffer pads: 2 bufs x {[0,4) U [516,520)} (wave-private)
  if (lane < 16) {
    int bu = lane >> 3, o = lane & 7;
    int j = (o < 4) ? o : (512 + o);
    bufs[w][bu][j] = __floats2half2_rn(0.f, 0.f);
  }
  __syncthreads();  // the ONLY barrier: publishes trig

  const __half2* src = xf2 + (size_t)(b * AA + a0) * RST;

  float4 r0, r1;  // staging registers: 32 B/lane = one row/wave
  auto ldrow = [&](int g) {
    const __half2* gp = src + (size_t)g * RST + 4 + lane * 8;
    r0 = *(const float4*)gp;        // global_load_dwordx4 x2, coalesced
    r1 = *(const float4*)(gp + 4);
  };
  auto strow = [&](int nb) {
    __half2* lp = &bufs[w][nb][4 + lane * 8];
    *(float4*)lp = r0;              // ds_write_b128 x2
    *(float4*)(lp + 4) = r1;
  };

  const int gx = tx * 64 + lane;    // [0,256)
  // EXACT f32 replication of jnp.linspace for the MASK (discontinuous);
  // p itself is continuity-safe.
  const float step = 2.0f / 511.0f;
  const float xg = __fadd_rn(-1.0f, __fmul_rn((float)gx, step));
  float dy[8];
#pragma unroll
  for (int kk = 0; kk < 8; ++kk) {
    int gy = ty * 32 + w + 4 * kk;
    dy[kk] = -__fadd_rn(-1.0f, __fmul_rn((float)gy, step));
  }

  const float Kb = 255.5f + 4.0f;   // +4 = row pad offset
  const __half2 hz2 = __floats2half2_rn(0.f, 0.f);
  v2f acc[8];
  __half2 gacc[8];
#pragma unroll
  for (int kk = 0; kk < 8; ++kk) { acc[kk] = (v2f){0.f, 0.f}; gacc[kk] = hz2; }

  ldrow(0);
  strow(0);

  for (int g = 0; g < 45; ++g) {
    const bool more = (g + 1 < 45);
    if (more) ldrow(g + 1);          // global prefetch covers compute below

    const float2 cs = trig[g];
    const float base = fmaf(xg, cs.x, Kb);
    const __half2* R = bufs[w][g & 1];
#pragma unroll
    for (int kk = 0; kk < 8; ++kk) {
      float P = fmaf(dy[kk], cs.y, base);   // in-circle: P in [4, 515]
      int   I = (int)P;                     // trunc == floor for P > 0
      I = min(max(I, 0), 518);              // v_med3: contain out-circle lanes
#if __has_builtin(__builtin_amdgcn_fractf)
      float wq = __builtin_amdgcn_fractf(P);
#else
      float wq = P - floorf(P);
#endif
      struct { __half2 a, b; } q;           // 8B @ 4B-align -> ds_read2_b32
      __builtin_memcpy(&q, R + I, 8);
      __half2 dv  = __hsub2(q.b, q.a);
      __half2 wh2 = __floats2half2_rn(wq, wq);
      gacc[kk] = __hadd2(gacc[kk], __hfma2(wh2, dv, q.a));
    }

    if (more) strow((g + 1) & 1);    // write other buffer; same-wave order ok

    if ((g % 5) == 4) {              // flush fp16 group acc (5 samples) to f32
#pragma unroll
      for (int kk = 0; kk < 8; ++kk) {
        float2 f = __half22float2(gacc[kk]);
        acc[kk].x += f.x;
        acc[kk].y += f.y;
        gacc[kk] = hz2;
      }
    }
  }

  // epilogue: per-pixel masks (exact f32 replication) + predicated atomics
  const int gxm  = 511 - gx;
  const float xgm = __fadd_rn(-1.0f, __fmul_rn((float)gxm, step));
  const float xx  = __fmul_rn(xg, xg);
  const float xxm = __fmul_rn(xgm, xgm);
#pragma unroll
  for (int kk = 0; kk < 8; ++kk) {
    int gy  = ty * 32 + w + 4 * kk;
    float yg = -dy[kk];
    float s0 = __fadd_rn(xx, __fmul_rn(yg, yg));
    if (s0 <= 1.0f)
      unsafeAtomicAdd(&out[((size_t)b * SS + gy) * SS + gx], acc[kk].x);
    int gym = 511 - gy;
    float ygm = __fadd_rn(-1.0f, __fmul_rn((float)gym, step));
    float s1 = __fadd_rn(xxm, __fmul_rn(ygm, ygm));
    if (s1 <= 1.0f)
      unsafeAtomicAdd(&out[((size_t)b * SS + gym) * SS + gxm], acc[kk].y);
  }
}

}  // namespace

extern "C" void kernel_launch(void* const* d_in, const int* in_sizes, int n_in,
                              void* d_out, int out_size, void* d_ws, size_t ws_size,
                              hipStream_t stream) {
  const float* x   = (const float*)d_in[0];
  float*       out = (float*)d_out;
  __half2*     xf2 = (__half2*)d_ws;  // [B*A][520] x 4B = 1.50 MB

  ramp_zero_kernel<<<dim3(AA / 2, BB), 256, 0, stream>>>(x, xf2, out);
  backproject_kernel<<<dim3(4, 16, 16), 256, 0, stream>>>(xf2, out);
}

// Round 15
// 97.080 us; speedup vs baseline: 1.2311x; 1.0160x over previous
//
#include <hip/hip_runtime.h>
#include <hip/hip_fp16.h>
#include <math.h>

namespace {

constexpr int BB  = 4;    // batch
constexpr int SS  = 512;  // detector bins == image size
constexpr int AA  = 180;  // angles
constexpr int RST = 520;  // row stride in __half2: [0,4) zeros, [4,516) data, [516,520) zeros

typedef float v2f __attribute__((ext_vector_type(2)));

// ---------------------------------------------------------------------------
// Kernel A: zero `out` + ramp filter + fp16 pair-pack into PADDED global rows.
//   row[4+j] = (half(y[j]), half(y[511-j])); row[0..3] = row[516..519] = 0.
// (R12/R13-verified, absmax 9.77e-4.)
// ---------------------------------------------------------------------------
__global__ __launch_bounds__(256) void ramp_zero_kernel(
    const float* __restrict__ x, __half2* __restrict__ xf2, float* __restrict__ out) {
  const int t = threadIdx.x;
  {  // zero out: 262144 float4 over 360 blocks
    const int bid = blockIdx.y * 90 + blockIdx.x;
    float4 z = make_float4(0.f, 0.f, 0.f, 0.f);
    for (int i = bid * 256 + t; i < (BB * SS * SS) / 4; i += 360 * 256)
      ((float4*)out)[i] = z;
  }

  __shared__ __align__(16) float xs[2][2][256];  // [col][m-parity][m>>1]
  __shared__ __align__(16) float G[2][528];      // per-parity scaled taps
  __shared__ float yb[2][512];                   // filtered rows (both cols)
  const int a0 = blockIdx.x * 2;
  const int b  = blockIdx.y;

  const float s  = (float)(M_PI / 360.0);
  const float cc = (float)(-2.0 / (M_PI * M_PI)) * s;
  for (int i = t; i < 528; i += 256) {
    { int kk = i;     float d = (float)(2 * kk - 511); G[0][i] = (kk < 512) ? cc / (d * d) : 0.0f; }
    { int kk = i + 1; float d = (float)(2 * kk - 511); G[1][i] = (kk < 512) ? cc / (d * d) : 0.0f; }
  }

  const float* xb = x + (size_t)b * (SS * AA) + a0;
  {
    int m = t;
    float2 v = *(const float2*)(xb + (size_t)m * AA);
    xs[0][m & 1][m >> 1] = v.x;  xs[1][m & 1][m >> 1] = v.y;
    m = t + 256;
    float2 v2 = *(const float2*)(xb + (size_t)m * AA);
    xs[0][m & 1][m >> 1] = v2.x; xs[1][m & 1][m >> 1] = v2.y;
  }
  __syncthreads();

  const int col = t >> 7;
  const int p   = (t >> 6) & 1;
  const int idx = t & 63;
  const float* Gp = G[p];
  const float* xv = xs[col][1 - p];

  float acc[4] = {0.f, 0.f, 0.f, 0.f};
  float W[8];  // W[s] = Gp[A0 + s], A0 = 4*idx + 252 - 4q; slot(r,d) = 3+r-d
  {
    const int A0 = 4 * idx + 252;
    float4 w0 = *(const float4*)(Gp + A0);
    float4 w1 = *(const float4*)(Gp + A0 + 4);
    W[0] = w0.x; W[1] = w0.y; W[2] = w0.z; W[3] = w0.w;
    W[4] = w1.x; W[5] = w1.y; W[6] = w1.z; W[7] = w1.w;
  }

#pragma unroll
  for (int q = 0; q < 64; ++q) {
    const float4 xq = *(const float4*)(xv + 4 * q);  // broadcast
    float4 nw;
    if (q != 63) nw = *(const float4*)(Gp + (4 * idx + 252 - 4 * (q + 1)));
#pragma unroll
    for (int r = 0; r < 4; ++r) {
      acc[r] = fmaf(W[3 + r], xq.x, acc[r]);
      acc[r] = fmaf(W[2 + r], xq.y, acc[r]);
      acc[r] = fmaf(W[1 + r], xq.z, acc[r]);
      acc[r] = fmaf(W[0 + r], xq.w, acc[r]);
    }
    if (q != 63) {
      W[7] = W[3]; W[6] = W[2]; W[5] = W[1]; W[4] = W[0];
      W[0] = nw.x; W[1] = nw.y; W[2] = nw.z; W[3] = nw.w;
    }
  }

  // self term -> LDS row (yb is a distinct array: no barrier needed before)
  const float selfc = 0.5f * s;
  const float* xsp = xs[col][p];
#pragma unroll
  for (int r = 0; r < 4; ++r)
    yb[col][p + 8 * idx + 2 * r] = fmaf(selfc, xsp[4 * idx + r], acc[r]);
  __syncthreads();

  // pack (fwd, rev) fp16 pairs into padded rows, coalesced 4B stores
  __half2* orow = xf2 + (size_t)(b * AA + a0) * RST;
#pragma unroll
  for (int e = 0; e < 2; ++e) {
    int j = t + e * 256;
#pragma unroll
    for (int c2 = 0; c2 < 2; ++c2)
      orow[c2 * RST + 4 + j] = __floats2half2_rn(yb[c2][j], yb[c2][511 - j]);
  }
  if (t < 16) {  // zero pads: 2 cols x {[0,4) U [516,520)}
    int c2 = t >> 3, o = t & 7;
    int j = (o < 4) ? o : (512 + o);
    orow[c2 * RST + j] = __floats2half2_rn(0.f, 0.f);
  }
}

// ---------------------------------------------------------------------------
// Kernel B: backprojection — wave-private LDS dbuf, DMA staging, no barriers.
// R14 vs R13 (41us, SQ_LDS_BANK_CONFLICT=2.67M from stride-32B ds_write_b128):
//  1. staging via global_load_lds (wave-uniform base = wave-private buffer is
//     legal): contiguous 2x1024B, NO ds_write (conflicts -> 0, ~7us DS-issue
//     gone). Wave-local ordering by explicit s_waitcnt vmcnt(2) (vmcnt
//     retires in order; only in-loop VMEM is the DMA).
//  2. med3 clamp removed: in-circle => P in [4,515] (|t|<=1 by C-S), reads hit
//     data/zero-pad; out-circle lanes read harmless LDS garbage, masked later.
//  3. v_cvt_pkrtz for the w half2 (1 instr; RTZ error <= 2^-11*|b-a|, negl.).
// 8 VALU + 1 ds_read2_b32 per pair-sample. Grid (4,16,16) = 4 blocks/CU.
// ---------------------------------------------------------------------------
__global__ __launch_bounds__(256, 4) void backproject_kernel(
    const __half2* __restrict__ xf2, float* __restrict__ out) {
  __shared__ __align__(16) __half2 bufs[4][2][RST];  // wave-private, 16.6 KB
  __shared__ float2 trig[45];

  const int t     = threadIdx.x;
  const int w     = t >> 6;
  const int lane  = t & 63;
  const int tx    = blockIdx.x;     // 0..3  x-tile (64 px, left half)
  const int ty    = blockIdx.y;     // 0..15 y-tile (32 rows of pairs)
  const int b     = blockIdx.z >> 2;
  const int chunk = blockIdx.z & 3;
  const int a0    = chunk * 45;

  // early-exit tiles fully outside the circle (block-uniform; before barrier)
  {
    const float step = 2.0f / 511.0f;
    float x0 = -1.0f + (float)(tx * 64) * step, x1 = -1.0f + (float)(tx * 64 + 63) * step;
    float y0 = -1.0f + (float)(ty * 32) * step, y1 = -1.0f + (float)(ty * 32 + 31) * step;
    float mx = (x0 <= 0.f && x1 >= 0.f) ? 0.f : fminf(fabsf(x0), fabsf(x1));
    float my = (y0 <= 0.f && y1 >= 0.f) ? 0.f : fminf(fabsf(y0), fabsf(y1));
    if (mx * mx + my * my > 1.0f) return;  // out already zeroed
  }

  if (t < 45) {
    float th = (float)(a0 + t) * (float)(M_PI / 180.0);
    float sn, cn;
    sincosf(th, &sn, &cn);
    trig[t] = make_float2(cn * 255.5f, sn * 255.5f);
  }
  // zero this wave's buffer pads: 2 bufs x {[0,4) U [516,520)} (wave-private)
  if (lane < 16) {
    int bu = lane >> 3, o = lane & 7;
    int j = (o < 4) ? o : (512 + o);
    bufs[w][bu][j] = __floats2half2_rn(0.f, 0.f);
  }
  __syncthreads();  // the ONLY barrier: publishes trig

  const __half2* src = xf2 + (size_t)(b * AA + a0) * RST;

  // DMA one row (2048B data) into this wave's buffer nb: two contiguous
  // 1024B segments; per-lane global addr, wave-uniform LDS base (+lane*16 HW).
  auto dma_row = [&](int g, int nb) {
    const __half2* gp = src + (size_t)g * RST + 4 + lane * 4;
    __builtin_amdgcn_global_load_lds(
        (const __attribute__((address_space(1))) void*)gp,
        (__attribute__((address_space(3))) void*)&bufs[w][nb][4], 16, 0, 0);
    __builtin_amdgcn_global_load_lds(
        (const __attribute__((address_space(1))) void*)(gp + 256),
        (__attribute__((address_space(3))) void*)&bufs[w][nb][260], 16, 0, 0);
  };

  const int gx = tx * 64 + lane;    // [0,256)
  // EXACT f32 replication of jnp.linspace for the MASK (discontinuous);
  // p itself is continuity-safe.
  const float step = 2.0f / 511.0f;
  const float xg = __fadd_rn(-1.0f, __fmul_rn((float)gx, step));
  float dy[8];
#pragma unroll
  for (int kk = 0; kk < 8; ++kk) {
    int gy = ty * 32 + w + 4 * kk;
    dy[kk] = -__fadd_rn(-1.0f, __fmul_rn((float)gy, step));
  }

  const float Kb = 255.5f + 4.0f;   // +4 = row pad offset
  const __half2 hz2 = __floats2half2_rn(0.f, 0.f);
  v2f acc[8];
  __half2 gacc[8];
#pragma unroll
  for (int kk = 0; kk < 8; ++kk) { acc[kk] = (v2f){0.f, 0.f}; gacc[kk] = hz2; }

  dma_row(0, 0);

  for (int g = 0; g < 45; ++g) {
    const bool more = (g + 1 < 45);
    if (more) dma_row(g + 1, (g + 1) & 1);
    // wait: all DMAs except the (g+1) row's 2 are retired => row g resident.
    if (more) __builtin_amdgcn_s_waitcnt(0x0F72);  // vmcnt(2) exp(7) lgkm(15)
    else      __builtin_amdgcn_s_waitcnt(0x0F70);  // vmcnt(0)

    const float2 cs = trig[g];
    const float base = fmaf(xg, cs.x, Kb);
    const __half2* R = bufs[w][g & 1];
#pragma unroll
    for (int kk = 0; kk < 8; ++kk) {
      float P = fmaf(dy[kk], cs.y, base);   // in-circle: P in [4, 515]
      int   I = (int)P;                     // trunc == floor for P > 0 lanes
#if __has_builtin(__builtin_amdgcn_fractf)
      float wq = __builtin_amdgcn_fractf(P);
#else
      float wq = P - floorf(P);
#endif
      struct { __half2 a, b; } q;           // 8B @ 4B-align -> ds_read2_b32
      __builtin_memcpy(&q, R + I, 8);
      __half2 dv = __hsub2(q.b, q.a);
      auto wr = __builtin_amdgcn_cvt_pkrtz(wq, wq);  // v_cvt_pkrtz_f16_f32
      __half2 wh2; __builtin_memcpy(&wh2, &wr, 4);
      gacc[kk] = __hadd2(gacc[kk], __hfma2(wh2, dv, q.a));
    }

    if ((g % 5) == 4) {              // flush fp16 group acc (5 samples) to f32
#pragma unroll
      for (int kk = 0; kk < 8; ++kk) {
        float2 f = __half22float2(gacc[kk]);
        acc[kk].x += f.x;
        acc[kk].y += f.y;
        gacc[kk] = hz2;
      }
    }
  }

  // epilogue: per-pixel masks (exact f32 replication) + predicated atomics
  const int gxm  = 511 - gx;
  const float xgm = __fadd_rn(-1.0f, __fmul_rn((float)gxm, step));
  const float xx  = __fmul_rn(xg, xg);
  const float xxm = __fmul_rn(xgm, xgm);
#pragma unroll
  for (int kk = 0; kk < 8; ++kk) {
    int gy  = ty * 32 + w + 4 * kk;
    float yg = -dy[kk];
    float s0 = __fadd_rn(xx, __fmul_rn(yg, yg));
    if (s0 <= 1.0f)
      unsafeAtomicAdd(&out[((size_t)b * SS + gy) * SS + gx], acc[kk].x);
    int gym = 511 - gy;
    float ygm = __fadd_rn(-1.0f, __fmul_rn((float)gym, step));
    float s1 = __fadd_rn(xxm, __fmul_rn(ygm, ygm));
    if (s1 <= 1.0f)
      unsafeAtomicAdd(&out[((size_t)b * SS + gym) * SS + gxm], acc[kk].y);
  }
}

}  // namespace

extern "C" void kernel_launch(void* const* d_in, const int* in_sizes, int n_in,
                              void* d_out, int out_size, void* d_ws, size_t ws_size,
                              hipStream_t stream) {
  const float* x   = (const float*)d_in[0];
  float*       out = (float*)d_out;
  __half2*     xf2 = (__half2*)d_ws;  // [B*A][520] x 4B = 1.50 MB

  ramp_zero_kernel<<<dim3(AA / 2, BB), 256, 0, stream>>>(x, xf2, out);
  backproject_kernel<<<dim3(4, 16, 16), 256, 0, stream>>>(xf2, out);
}

// Round 16
// 91.617 us; speedup vs baseline: 1.3046x; 1.0596x over previous
//
#include <hip/hip_runtime.h>
#include <hip/hip_fp16.h>
#include <math.h>

namespace {

constexpr int BB  = 4;    // batch
constexpr int SS  = 512;  // detector bins == image size
constexpr int AA  = 180;  // angles
constexpr int NJ  = 91;   // jobs: 89 pairs (a,180-a), a=1..89, + singles {0,90}
constexpr int RST = 520;  // row stride in 8B entries: [0,4) zeros, [4,516) data, [516,520) zeros

// ---------------------------------------------------------------------------
// Kernel A: zero `out` + ramp filter + 4-wide fp16 pack into padded rows.
// Job k: angles a1 = k+1, a2 = 179-k (k<89); singles k=89 -> a=0, k=90 -> a=90
// (a2 rows packed as zeros). Row entry[4+j] = (yA[j], yA[511-j], yB[j],
// yB[511-j]) as 4 x fp16 = 8 B. Conv math identical to R4-verified version.
// ---------------------------------------------------------------------------
__global__ __launch_bounds__(256) void ramp_zero_kernel(
    const float* __restrict__ x, uint2* __restrict__ xf, float* __restrict__ out) {
  const int t = threadIdx.x;
  const int k = blockIdx.x;   // job
  const int b = blockIdx.y;
  {  // zero out: 262144 float4 over 364 blocks
    const int bid = b * NJ + k;
    float4 z = make_float4(0.f, 0.f, 0.f, 0.f);
    for (int i = bid * 256 + t; i < (BB * SS * SS) / 4; i += 364 * 256)
      ((float4*)out)[i] = z;
  }
  const int a1 = (k < 89) ? (k + 1) : ((k == 89) ? 0 : 90);
  const int a2 = (k < 89) ? (179 - k) : a1;

  __shared__ __align__(16) float xs[2][2][256];  // [col][m-parity][m>>1]
  __shared__ __align__(16) float G[2][528];      // per-parity scaled taps
  __shared__ float yb[2][512];                   // filtered rows (both cols)

  const float s  = (float)(M_PI / 360.0);
  const float cc = (float)(-2.0 / (M_PI * M_PI)) * s;
  for (int i = t; i < 528; i += 256) {
    { int kk = i;     float d = (float)(2 * kk - 511); G[0][i] = (kk < 512) ? cc / (d * d) : 0.0f; }
    { int kk = i + 1; float d = (float)(2 * kk - 511); G[1][i] = (kk < 512) ? cc / (d * d) : 0.0f; }
  }

  const float* xb = x + (size_t)b * (SS * AA);
  {
    int m = t;
    xs[0][m & 1][m >> 1] = xb[(size_t)m * AA + a1];
    xs[1][m & 1][m >> 1] = xb[(size_t)m * AA + a2];
    m = t + 256;
    xs[0][m & 1][m >> 1] = xb[(size_t)m * AA + a1];
    xs[1][m & 1][m >> 1] = xb[(size_t)m * AA + a2];
  }
  __syncthreads();

  const int col = t >> 7;
  const int p   = (t >> 6) & 1;
  const int idx = t & 63;
  const float* Gp = G[p];
  const float* xv = xs[col][1 - p];

  float acc[4] = {0.f, 0.f, 0.f, 0.f};
  float W[8];  // W[s] = Gp[A0 + s], A0 = 4*idx + 252 - 4q; slot(r,d) = 3+r-d
  {
    const int A0 = 4 * idx + 252;
    float4 w0 = *(const float4*)(Gp + A0);
    float4 w1 = *(const float4*)(Gp + A0 + 4);
    W[0] = w0.x; W[1] = w0.y; W[2] = w0.z; W[3] = w0.w;
    W[4] = w1.x; W[5] = w1.y; W[6] = w1.z; W[7] = w1.w;
  }

#pragma unroll
  for (int q = 0; q < 64; ++q) {
    const float4 xq = *(const float4*)(xv + 4 * q);  // broadcast
    float4 nw;
    if (q != 63) nw = *(const float4*)(Gp + (4 * idx + 252 - 4 * (q + 1)));
#pragma unroll
    for (int r = 0; r < 4; ++r) {
      acc[r] = fmaf(W[3 + r], xq.x, acc[r]);
      acc[r] = fmaf(W[2 + r], xq.y, acc[r]);
      acc[r] = fmaf(W[1 + r], xq.z, acc[r]);
      acc[r] = fmaf(W[0 + r], xq.w, acc[r]);
    }
    if (q != 63) {
      W[7] = W[3]; W[6] = W[2]; W[5] = W[1]; W[4] = W[0];
      W[0] = nw.x; W[1] = nw.y; W[2] = nw.z; W[3] = nw.w;
    }
  }

  const float selfc = 0.5f * s;
  const float* xsp = xs[col][p];
#pragma unroll
  for (int r = 0; r < 4; ++r)
    yb[col][p + 8 * idx + 2 * r] = fmaf(selfc, xsp[4 * idx + r], acc[r]);
  __syncthreads();

  // write packed rows: 8 B per entry, coalesced
  uint2* orow = xf + (size_t)(b * NJ + k) * RST;
  const bool dual = (k < 89);
#pragma unroll
  for (int e = 0; e < 2; ++e) {
    int j = t + e * 256;
    __half2 lo = __floats2half2_rn(yb[0][j], yb[0][511 - j]);
    __half2 hi = dual ? __floats2half2_rn(yb[1][j], yb[1][511 - j])
                      : __floats2half2_rn(0.f, 0.f);
    uint2 u;
    __builtin_memcpy(&u.x, &lo, 4);
    __builtin_memcpy(&u.y, &hi, 4);
    orow[4 + j] = u;
  }
  if (t < 8) orow[(t < 4) ? t : (512 + t)] = make_uint2(0u, 0u);
}

// ---------------------------------------------------------------------------
// Kernel B: backprojection, FOUR-FOLD symmetry (point reflection x theta-pair).
// Thread owns pixel quad {(gx,gy),(gxm,gym),(gx,gym),(gxm,gy)}, gx,gy<256.
// Per job (angle pair a, b=180-a): two 16B ds_read2_b64 at index(t1),index(u)
// serve all 8 pixel-angle samples (lo half2 = row a fwd/rev, hi = row b):
//   read@t1: lo->(x,y)@a,(-x,-y)@a   hi->(-x,y)@b,(x,-y)@b
//   read@u : lo->(x,-y)@a,(-x,y)@a   hi->(-x,-y)@b,(x,y)@b
// 22 VALU + 2 DS per 8 samples (R15: 32 + 4). Wave-private LDS dbuf via
// global_load_lds (4x1024B + 1 predicated 64B), s_waitcnt vmcnt(5), 0 barriers
// in the loop. 4 packed fp16 accs (per-read layout, no swizzle), f32 flush
// every 5 jobs. Grid (4,16,16) = 1024 blocks = 4/CU; LDS 33.5 KB.
// ---------------------------------------------------------------------------
__global__ __launch_bounds__(256, 4) void backproject_kernel(
    const uint2* __restrict__ xf, float* __restrict__ out) {
  __shared__ __align__(16) uint2 bufs[4][2][RST];  // 33,280 B, wave-private
  __shared__ float2 trigS[23];

  const int t    = threadIdx.x;
  const int w    = t >> 6;
  const int lane = t & 63;
  const int tx   = blockIdx.x;     // 0..3  gx tile (64)
  const int ty   = blockIdx.y;     // 0..15 gy tile (16)
  const int b    = blockIdx.z >> 2;
  const int c    = blockIdx.z & 3; // job chunk (strided)
  const int njobs = (c < 3) ? 23 : 22;

  const float step = 2.0f / 511.0f;
  // early-exit quad tiles fully outside the circle (all 4 quadrant images
  // share |x|,|y| up to ulps; conservative continuous test)
  {
    float x1 = -1.0f + (float)(tx * 64 + 63) * step;  // quadrant: xg<0 always
    float y1 = -1.0f + (float)(ty * 16 + 15) * step;
    if (x1 * x1 + y1 * y1 > 1.0f) return;  // out already zeroed
  }

  if (t < njobs) {
    int k = c + 4 * t;
    int a = (k < 89) ? (k + 1) : ((k == 89) ? 0 : 90);
    float sn, cn;
    sincosf((float)a * (float)(M_PI / 180.0), &sn, &cn);
    trigS[t] = make_float2(cn * 255.5f, sn * 255.5f);
  }
  __syncthreads();

  const uint2* rows = xf + (size_t)b * NJ * RST;
  auto dma = [&](int i, int nb) {
    const char* g0 = (const char*)(rows + (size_t)(c + 4 * i) * RST);
    char* l0 = (char*)&bufs[w][nb][0];
#pragma unroll
    for (int sg = 0; sg < 4; ++sg)
      __builtin_amdgcn_global_load_lds(
          (const __attribute__((address_space(1))) void*)(g0 + sg * 1024 + lane * 16),
          (__attribute__((address_space(3))) void*)(l0 + sg * 1024), 16, 0, 0);
    if (lane < 4)
      __builtin_amdgcn_global_load_lds(
          (const __attribute__((address_space(1))) void*)(g0 + 4096 + lane * 16),
          (__attribute__((address_space(3))) void*)(l0 + 4096), 16, 0, 0);
  };

  const int gx = tx * 64 + lane;    // [0,256)
  // EXACT f32 replication of jnp.linspace for the MASK; p is continuity-safe.
  const float xg = __fadd_rn(-1.0f, __fmul_rn((float)gx, step));
  float yg[4];
#pragma unroll
  for (int kk = 0; kk < 4; ++kk)
    yg[kk] = __fadd_rn(-1.0f, __fmul_rn((float)(ty * 16 + w * 4 + kk), step));

  const float Kb = 255.5f + 4.0f;   // +4 = left pad
  const __half2 hz = __floats2half2_rn(0.f, 0.f);
  float f00[4] = {0, 0, 0, 0}, f11[4] = {0, 0, 0, 0};
  float f01[4] = {0, 0, 0, 0}, f10[4] = {0, 0, 0, 0};
  __half2 accA[4], accB[4], accC[4], accD[4];
#pragma unroll
  for (int kk = 0; kk < 4; ++kk) { accA[kk] = hz; accB[kk] = hz; accC[kk] = hz; accD[kk] = hz; }

  dma(0, 0);

  for (int i = 0; i < njobs; ++i) {
    const bool more = (i + 1 < njobs);
    if (more) {
      dma(i + 1, (i + 1) & 1);
      __builtin_amdgcn_s_waitcnt(0x0F75);  // vmcnt(5): job i's 5 DMAs retired
    } else {
      __builtin_amdgcn_s_waitcnt(0x0F70);  // vmcnt(0)
    }

    const float2 cs = trigS[i];
    const float m = fmaf(xg, cs.x, Kb);
    const uint2* R = bufs[w][i & 1];
#pragma unroll
    for (int kk = 0; kk < 4; ++kk) {
      float P1 = fmaf(-yg[kk], cs.y, m);   // t1 = x c - y s (padded coords)
      float Pu = fmaf( yg[kk], cs.y, m);   // u  = x c + y s
      int I1 = (int)P1, Iu = (int)Pu;      // trunc==floor in-circle (P>=4)
#if __has_builtin(__builtin_amdgcn_fractf)
      float w1 = __builtin_amdgcn_fractf(P1);
      float wu = __builtin_amdgcn_fractf(Pu);
#else
      float w1 = P1 - floorf(P1);
      float wu = Pu - floorf(Pu);
#endif
      auto w1r = __builtin_amdgcn_cvt_pkrtz(w1, w1);
      auto wur = __builtin_amdgcn_cvt_pkrtz(wu, wu);
      __half2 w1h, wuh;
      __builtin_memcpy(&w1h, &w1r, 4);
      __builtin_memcpy(&wuh, &wur, 4);
      struct alignas(8) Q { __half2 lo, hi, lo2, hi2; } q1, qu;
      __builtin_memcpy(&q1, R + I1, 16);   // ds_read2_b64
      __builtin_memcpy(&qu, R + Iu, 16);
      accA[kk] = __hadd2(accA[kk], __hfma2(w1h, __hsub2(q1.lo2, q1.lo), q1.lo));
      accB[kk] = __hadd2(accB[kk], __hfma2(w1h, __hsub2(q1.hi2, q1.hi), q1.hi));
      accC[kk] = __hadd2(accC[kk], __hfma2(wuh, __hsub2(qu.lo2, qu.lo), qu.lo));
      accD[kk] = __hadd2(accD[kk], __hfma2(wuh, __hsub2(qu.hi2, qu.hi), qu.hi));
    }

    if ((i % 5) == 4 || i == njobs - 1) {  // flush fp16 accs (<=5 jobs) to f32
#pragma unroll
      for (int kk = 0; kk < 4; ++kk) {
        float2 fa = __half22float2(accA[kk]);  // ((x,y)@a,   (-x,-y)@a)
        float2 fb = __half22float2(accB[kk]);  // ((-x,y)@b,  (x,-y)@b)
        float2 fc = __half22float2(accC[kk]);  // ((x,-y)@a,  (-x,y)@a)
        float2 fd = __half22float2(accD[kk]);  // ((-x,-y)@b, (x,y)@b)
        f00[kk] += fa.x + fd.y;
        f11[kk] += fa.y + fd.x;
        f10[kk] += fb.x + fc.y;
        f01[kk] += fb.y + fc.x;
        accA[kk] = hz; accB[kk] = hz; accC[kk] = hz; accD[kk] = hz;
      }
    }
  }

  // epilogue: per-pixel masks (exact f32 replication) + predicated atomics
  const int gxm  = 511 - gx;
  const float xgm = __fadd_rn(-1.0f, __fmul_rn((float)gxm, step));
  const float xx  = __fmul_rn(xg, xg);
  const float xxm = __fmul_rn(xgm, xgm);
#pragma unroll
  for (int kk = 0; kk < 4; ++kk) {
    int gy = ty * 16 + w * 4 + kk, gym = 511 - gy;
    float ygv = yg[kk];
    float ygm = __fadd_rn(-1.0f, __fmul_rn((float)gym, step));
    float yy  = __fmul_rn(ygv, ygv), yym = __fmul_rn(ygm, ygm);
    if (__fadd_rn(xx,  yy)  <= 1.0f) unsafeAtomicAdd(&out[((size_t)b * SS + gy ) * SS + gx ], f00[kk]);
    if (__fadd_rn(xxm, yym) <= 1.0f) unsafeAtomicAdd(&out[((size_t)b * SS + gym) * SS + gxm], f11[kk]);
    if (__fadd_rn(xx,  yym) <= 1.0f) unsafeAtomicAdd(&out[((size_t)b * SS + gym) * SS + gx ], f01[kk]);
    if (__fadd_rn(xxm, yy)  <= 1.0f) unsafeAtomicAdd(&out[((size_t)b * SS + gy ) * SS + gxm], f10[kk]);
  }
}

}  // namespace

extern "C" void kernel_launch(void* const* d_in, const int* in_sizes, int n_in,
                              void* d_out, int out_size, void* d_ws, size_t ws_size,
                              hipStream_t stream) {
  const float* x   = (const float*)d_in[0];
  float*       out = (float*)d_out;
  uint2*       xf  = (uint2*)d_ws;  // [B*91][520] x 8B = 1.51 MB

  ramp_zero_kernel<<<dim3(NJ, BB), 256, 0, stream>>>(x, xf, out);
  backproject_kernel<<<dim3(4, 16, 16), 256, 0, stream>>>(xf, out);
}